// Round 14
// baseline (167.556 us; speedup 1.0000x reference)
//
#include <hip/hip_runtime.h>

#define NTOK 4096
#define NBH  32
// Symmetric-compressed feature rows:
//   [0,32)    linear k_i                          (weight a1 = 1)
//   [32,512)  s-blocks s=1..15: k_i * k_{(i+s)&31} (weight 1 = 2*a2, pair once)
//   [512,528) s=16:     k_i * k_{i+16}, i<16       (weight 1)
//   [528,560) diagonal  0.5 * k_i^2                (weight a2 = 0.5)
//   560       const 1                              (a0 term)
//   [561,576) pad (zero)
#define NF   576
#define NE   33
#define NKT  18
#define GTF_BH (NKT * 3 * 64 * 8)   // 27648 halves per bh
#define GTF_HALF (9 * 3 * 64 * 8)   // 13824 halves per staging phase
#define KC   16
#define NSTG 2                       // (NTOK/KC)/128
#define NVB  (KC * NBH)              // 512 blocks

typedef _Float16 half_t;
typedef _Float16 half8 __attribute__((ext_vector_type(8)));
typedef _Float16 half4v __attribute__((ext_vector_type(4)));
typedef float f32x4 __attribute__((ext_vector_type(4)));
typedef unsigned int u32;

#define MFMA16(A,B,C) __builtin_amdgcn_mfma_f32_16x16x32_f16((A),(B),(C),0,0,0)

// async 16B global->LDS: lds dst = wave-uniform base + lane*16
#define ASYNC_CP16(dst_lds, src_glb) \
    __builtin_amdgcn_global_load_lds( \
        (const __attribute__((address_space(1))) u32*)(const void*)(src_glb), \
        (__attribute__((address_space(3))) u32*)(void*)(dst_lds), 16, 0, 0)

static __device__ __forceinline__ half8 splat8(half_t x) {
    return (half8){x, x, x, x, x, x, x, x};
}

// LDS group-swizzle for ta's transpose staging.
static __device__ __forceinline__ int FS(int d) { return (d + (d >> 3)) & 15; }

// ---------------------------------------------------------------------------
// TA: fused transpose + G-build (r9/r12-proven 4-wave body) + FUSED REDUCE:
// after writing its P plane, each block bumps a per-bh device-scope counter;
// the 16th (last) block for a bh reduces that bh's 16 planes into GtF
// fragment order (identical arithmetic/order to the old ar_kernel).
// Cross-XCD visibility per Guideline 16: ACQ_REL agent-scope atomic +
// __threadfence() before the P reads.
// ---------------------------------------------------------------------------
__global__ __launch_bounds__(256, 2)
void ta_kernel(const float* __restrict__ kin, const float* __restrict__ vin,
               half_t* __restrict__ P, half_t* __restrict__ GtF,
               u32* __restrict__ done)
{
    __shared__ __align__(16) half_t kb0[2 * 4096];
    __shared__ __align__(16) half_t vb0[2 * 4096];
    __shared__ u32 lastflag;

    const int vb = blockIdx.x;
    const int bh = vb & (NBH - 1), kc = vb >> 5;
    const int t = threadIdx.x;
    const int w = t >> 6, lane = t & 63, l16 = lane & 15, quad = lane >> 4;
    const int pw = w * 144;
    const half8 h05 = splat8((half_t)0.5f);

    f32x4 acc[9][3];
    #pragma unroll
    for (int m = 0; m < 9; ++m)
        #pragma unroll
        for (int e = 0; e < 3; ++e)
            acc[m][e] = (f32x4){0.f, 0.f, 0.f, 0.f};

    // rotated-row metadata for s-block tiles
    int rotoff[9], rotsalt[9];
    #pragma unroll
    for (int mt = 0; mt < 9; ++mt) {
        const int pm = pw + mt * 16;
        int ro = 0, rs = 0;
        if (pm >= 32 && pm < 512) {
            const int s  = 1 + ((pm - 32) >> 5);
            const int i0 = (pm - 32) & 31;
            const int r  = (i0 + l16 + s) & 31;
            ro = r * 128;
            rs = FS(r);
        }
        rotoff[mt] = ro;
        rotsalt[mt] = rs;
    }
    const int sh0 = FS(l16), sh1 = FS(l16 + 16);

    const size_t fbase = ((size_t)bh * NTOK + kc * 256) * 32;  // float index
    const float4* k4 = (const float4*)kin + fbase / 4;
    const float4* v4 = (const float4*)vin + fbase / 4;

    float kaf[16], vaf[16];
    auto loadst = [&](int s) {
        const int base = s * 1024;   // 128 tokens * 8 float4/token
        #pragma unroll
        for (int r = 0; r < 4; ++r) {
            float4 kk = k4[base + t + 256 * r];
            float4 vv = v4[base + t + 256 * r];
            kaf[4*r+0] = kk.x; kaf[4*r+1] = kk.y; kaf[4*r+2] = kk.z; kaf[4*r+3] = kk.w;
            vaf[4*r+0] = vv.x; vaf[4*r+1] = vv.y; vaf[4*r+2] = vv.z; vaf[4*r+3] = vv.w;
        }
    };
    auto writest = [&](int buf) {
        half_t* kb = kb0 + buf * 4096;
        half_t* vb2 = vb0 + buf * 4096;
        #pragma unroll
        for (int r = 0; r < 4; ++r) {
            const int fi = t + 256 * r;
            const int n = fi >> 3, d4 = fi & 7;
            const int c = n >> 3, j = n & 7;
            #pragma unroll
            for (int i = 0; i < 4; ++i) {
                const int d = 4 * d4 + i;
                const int a = d * 128 + ((c ^ FS(d)) << 3) + j;
                kb[a] = (half_t)kaf[4*r+i];
                vb2[a] = (half_t)vaf[4*r+i];
            }
        }
    };
    auto compute = [&](int buf) {
        const half_t* kb = kb0 + buf * 4096;
        const half_t* vbp = vb0 + buf * 4096;
        #pragma unroll
        for (int kk = 0; kk < 4; ++kk) {
            const int c = kk * 4 + quad;
            half8 kj0 = *(const half8*)&kb[l16 * 128 + ((c ^ sh0) << 3)];
            half8 kj1 = *(const half8*)&kb[(l16 + 16) * 128 + ((c ^ sh1) << 3)];
            half8 bf0 = *(const half8*)&vbp[l16 * 128 + ((c ^ sh0) << 3)];
            half8 bf1 = *(const half8*)&vbp[(l16 + 16) * 128 + ((c ^ sh1) << 3)];
            half_t onec = (l16 == 0) ? (half_t)1 : (half_t)0;
            half8 bf2 = splat8(onec);
            #pragma unroll
            for (int mt = 0; mt < 9; ++mt) {
                const int pm = pw + mt * 16;
                half8 af;
                if (pm < 32) {
                    af = pm ? kj1 : kj0;                       // linear
                } else if (pm < 512) {
                    half8 rot = *(const half8*)&kb[rotoff[mt] + ((c ^ rotsalt[mt]) << 3)];
                    af = (((pm - 32) & 16) ? kj1 : kj0) * rot; // pair {i, i+s}
                } else if (pm == 512) {
                    af = kj0 * kj1;                            // s=16 pairs
                } else if (pm == 528) {
                    af = (kj0 * h05) * kj0;                    // diag i<16
                } else if (pm == 544) {
                    af = (kj1 * h05) * kj1;                    // diag i>=16
                } else {
                    af = bf2;                                  // const row (560)
                }
                acc[mt][0] = MFMA16(af, bf0, acc[mt][0]);
                acc[mt][1] = MFMA16(af, bf1, acc[mt][1]);
                acc[mt][2] = MFMA16(af, bf2, acc[mt][2]);
            }
        }
    };

    loadst(0);
    writest(0);
    __syncthreads();
    for (int st = 0; st < NSTG; ++st) {
        const int cur = st & 1;
        if (st + 1 < NSTG) loadst(st + 1);     // issue early: hides under MFMAs
        compute(cur);
        if (st + 1 < NSTG) { writest(cur ^ 1); __syncthreads(); }
    }

    half_t* Pb = P + ((size_t)kc * NBH + bh) * NE * NF;
    #pragma unroll
    for (int mt = 0; mt < 9; ++mt) {
        int p0 = pw + mt * 16 + quad * 4;
        half4v h0 = {(half_t)acc[mt][0][0], (half_t)acc[mt][0][1],
                     (half_t)acc[mt][0][2], (half_t)acc[mt][0][3]};
        half4v h1 = {(half_t)acc[mt][1][0], (half_t)acc[mt][1][1],
                     (half_t)acc[mt][1][2], (half_t)acc[mt][1][3]};
        *(half4v*)&Pb[(size_t)l16 * NF + p0] = h0;
        *(half4v*)&Pb[(size_t)(l16 + 16) * NF + p0] = h1;
        if (l16 == 0) {
            half4v h2 = {(half_t)acc[mt][2][0], (half_t)acc[mt][2][1],
                         (half_t)acc[mt][2][2], (half_t)acc[mt][2][3]};
            *(half4v*)&Pb[(size_t)32 * NF + p0] = h2;
        }
    }

    // ---- fused reduce: last block per bh sums the 16 planes into GtF ----
    __syncthreads();   // all P stores drained (vmcnt 0 before barrier)
    if (t == 0) {
        __threadfence();   // release: publish this block's P plane
        u32 old = __hip_atomic_fetch_add(&done[bh], 1u, __ATOMIC_ACQ_REL,
                                         __HIP_MEMORY_SCOPE_AGENT);
        lastflag = (old == KC - 1) ? 1u : 0u;
    }
    __syncthreads();
    if (lastflag) {
        __threadfence();   // acquire side: invalidate stale cache lines
        const int NP8B = NE * NF / 8;   // 2376
        for (int idx = t; idx < NP8B; idx += 256) {
            float s[8] = {0.f, 0.f, 0.f, 0.f, 0.f, 0.f, 0.f, 0.f};
            for (int c = 0; c < KC; ++c) {
                half8 h = *(const half8*)&P[((size_t)c * NBH + bh) * NE * NF
                                            + (size_t)idx * 8];
                #pragma unroll
                for (int j = 0; j < 8; ++j) s[j] += (float)h[j];
            }
            half8 o;
            #pragma unroll
            for (int j = 0; j < 8; ++j) o[j] = (half_t)s[j];
            const int e = idx / 72;              // NF/8 = 72
            const int p8 = idx - e * 72;
            const int kt = p8 >> 2, qd = p8 & 3;
            const int rr = e >> 4, le = e & 15;  // e==32 -> rr=2, le=0
            size_t dst8 = (size_t)bh * (GTF_BH / 8)
                        + (size_t)(kt * 3 + rr) * 64 + qd * 16 + le;
            *(half8*)&GtF[dst8 * 8] = o;
        }
    }
}

// ---------------------------------------------------------------------------
// B: out[n][e] = (phi(q_n).G[:,e]) / (phi(q_n).G[:,32]) via f16 MFMA over
// 18 feature chunks. GtF bh-slice staged into LDS via global_load_lds in two
// phases; fragments via contiguous ds_read_b128. (r9/r12-measured; kept.)
// ---------------------------------------------------------------------------
__global__ __launch_bounds__(256)
void b_kernel(const float* __restrict__ qin, const half_t* __restrict__ GtF,
              float* __restrict__ out)
{
    const int bh = blockIdx.x, mbq = blockIdx.y;   // 32 x 16
    const int t = threadIdx.x, w = t >> 6, lane = t & 63;
    const int l16 = lane & 15, quad = lane >> 4;
    __shared__ __align__(16) half_t qs2[256 * 56];     // 28672 B
    __shared__ __align__(16) half_t gs[GTF_HALF];      // 27648 B (9 kt)
    __shared__ float denl[256];                        // 1024 B
    const size_t nbase = (size_t)bh * NTOK + mbq * 256;

    // cooperative GtF staging: 27 chunks of 1 KB (64 lanes x 16 B), linear copy
    const half_t* Gsrc = GtF + (size_t)bh * GTF_BH + (size_t)lane * 8;
    auto stage = [&](int phase) {
        const half_t* src = Gsrc + phase * GTF_HALF;
        #pragma unroll
        for (int i = 0; i < 7; ++i) {
            const int c = w + 4 * i;
            if (c < 27)
                ASYNC_CP16(gs + c * 512, src + c * 512);
        }
    };
    stage(0);   // kt 0..8 in flight; hides under the q staging below

    const float4* q4 = (const float4*)(qin + nbase * 32);
    #pragma unroll
    for (int r = 0; r < 8; ++r) {
        int f4 = t + 256 * r, n = f4 >> 3, d4 = f4 & 7;
        float4 vv = q4[f4];
        half4v h = {(half_t)vv.x, (half_t)vv.y, (half_t)vv.z, (half_t)vv.w};
        *(half4v*)&qs2[n * 56 + d4 * 4] = h;
        if (d4 < 4) *(half4v*)&qs2[n * 56 + 32 + d4 * 4] = h;  // wrap dims 0..15
    }
    __syncthreads();   // drains async copies (vmcnt) + qs2 writes

    const int rbase = w * 64;
    int tb[4];
    #pragma unroll
    for (int mt = 0; mt < 4; ++mt) tb[mt] = (rbase + mt * 16 + l16) * 56;

    half8 vq[4], hv[4], gv[4];
    #pragma unroll
    for (int mt = 0; mt < 4; ++mt) {
        const int qb = tb[mt] + quad * 8;
        vq[mt] = *(const half8*)&qs2[qb];
        hv[mt] = *(const half8*)&qs2[qb + 8];
        gv[mt] = *(const half8*)&qs2[qb + 16];
    }

    f32x4 acc[3][4];
    #pragma unroll
    for (int a = 0; a < 3; ++a)
        #pragma unroll
        for (int b = 0; b < 4; ++b)
            acc[a][b] = (f32x4){0.f, 0.f, 0.f, 0.f};

    // fragment read from LDS: contiguous 16B/lane (conflict-free b128 pattern)
#define LDB(ktL, B) do { \
    _Pragma("unroll") \
    for (int rr = 0; rr < 3; ++rr) \
        (B)[rr] = *(const half8*)&gs[(((ktL) * 3 + rr) * 64 + lane) * 8]; \
} while (0)

#define DO_MFMA(AF, B) do { \
    _Pragma("unroll") \
    for (int mt = 0; mt < 4; ++mt) { \
        acc[0][mt] = MFMA16((AF)[mt], (B)[0], acc[0][mt]); \
        acc[1][mt] = MFMA16((AF)[mt], (B)[1], acc[1][mt]); \
        acc[2][mt] = MFMA16((AF)[mt], (B)[2], acc[2][mt]); \
    } \
} while (0)

#define QCHUNK(S, KTL) do { \
    half8 Bc[3]; \
    LDB((KTL), Bc); \
    half8 af[4]; \
    _Pragma("unroll") \
    for (int mt = 0; mt < 4; ++mt) { \
        half8 lo = ((S) < 8) ? vq[mt] : hv[mt]; \
        half8 hi = ((S) < 8) ? hv[mt] : gv[mt]; \
        half8 rot = __builtin_shufflevector(lo, hi, \
            ((S) & 7) + 0, ((S) & 7) + 1, ((S) & 7) + 2, ((S) & 7) + 3, \
            ((S) & 7) + 4, ((S) & 7) + 5, ((S) & 7) + 6, ((S) & 7) + 7); \
        af[mt] = vq[mt] * rot; \
    } \
    DO_MFMA(af, Bc); \
} while (0)

    // ---- phase A: kt 0..8 (resident in gs) ----
    {   // kt = 0: linear features
        half8 Bc[3];
        LDB(0, Bc);
        DO_MFMA(vq, Bc);
    }
    QCHUNK(1, 1);  QCHUNK(2, 2);  QCHUNK(3, 3);  QCHUNK(4, 4);
    QCHUNK(5, 5);  QCHUNK(6, 6);  QCHUNK(7, 7);  QCHUNK(8, 8);

    // ---- restage: kt 9..17 ----
    __syncthreads();   // all waves done reading phase-A gs
    stage(1);
    __syncthreads();   // copies drained (vmcnt waited before barrier)

    // ---- phase B: kt 9..17 (local indices 0..8) ----
    QCHUNK(9, 0);  QCHUNK(10, 1); QCHUNK(11, 2); QCHUNK(12, 3);
    QCHUNK(13, 4); QCHUNK(14, 5); QCHUNK(15, 6);

    {   // kt = 16 (local 7): quads 0,1: s16 pairs; quads 2,3: diag blocks 0,1
        half8 Bc[3];
        LDB(7, Bc);
        half8 af[4];
        #pragma unroll
        for (int mt = 0; mt < 4; ++mt) {
            const int off = tb[mt] + ((quad >= 2) ? (quad - 2) : quad) * 8;
            half8 Ld = *(const half8*)&qs2[off];
            af[mt] = (quad < 2) ? (vq[mt] * gv[mt]) : (Ld * Ld);
        }
        DO_MFMA(af, Bc);
    }
    {   // kt = 17 (local 8): quads 0,1: diag blocks 2,3; quad 2: const e0; quad 3: pad
        half8 Bc[3];
        LDB(8, Bc);
        const half8 zero = {};
        half8 c10 = {};
        c10[0] = (half_t)1;
        half8 af[4];
        #pragma unroll
        for (int mt = 0; mt < 4; ++mt) {
            half8 d = gv[mt] * gv[mt];
            af[mt] = (quad < 2) ? d : ((quad == 2) ? c10 : zero);
        }
        DO_MFMA(af, Bc);
    }
#undef QCHUNK
#undef DO_MFMA
#undef LDB

    if (l16 == 0) {
        #pragma unroll
        for (int mt = 0; mt < 4; ++mt)
            #pragma unroll
            for (int r = 0; r < 4; ++r)
                denl[rbase + mt * 16 + quad * 4 + r] = acc[2][mt][r];
    }
    __syncthreads();
    #pragma unroll
    for (int mt = 0; mt < 4; ++mt) {
        float inv[4];
        #pragma unroll
        for (int r = 0; r < 4; ++r)
            inv[r] = __builtin_amdgcn_rcpf(denl[rbase + mt * 16 + quad * 4 + r]);
        #pragma unroll
        for (int r = 0; r < 4; ++r) {
            size_t ro = (nbase + rbase + mt * 16 + quad * 4 + r) * 32;
            out[ro + l16] = acc[0][mt][r] * inv[r];
            out[ro + l16 + 16] = acc[1][mt][r] * inv[r];
        }
    }
}

// ---------------------------------------------------------------------------
extern "C" void kernel_launch(void* const* d_in, const int* in_sizes, int n_in,
                              void* d_out, int out_size, void* d_ws, size_t ws_size,
                              hipStream_t stream)
{
    const float* q = (const float*)d_in[0];
    const float* k = (const float*)d_in[1];
    const float* v = (const float*)d_in[2];
    float* out = (float*)d_out;

    const size_t planeHalves = (size_t)NBH * NE * NF;      // 608256
    half_t* P = (half_t*)d_ws;                             // 16 planes: 19.5 MB
    half_t* GtF = P + (size_t)KC * planeHalves;            // 1.77 MB
    u32* done = (u32*)(GtF + (size_t)NBH * GTF_BH);        // 32 counters

    hipMemsetAsync(done, 0, NBH * sizeof(u32), stream);
    ta_kernel<<<dim3(NVB), 256, 0, stream>>>(k, v, P, GtF, done);
    b_kernel<<<dim3(NBH, 16), 256, 0, stream>>>(q, GtF, out);
}

// Round 15
// 118.792 us; speedup vs baseline: 1.4105x; 1.4105x over previous
//
#include <hip/hip_runtime.h>

#define NTOK 4096
#define NBH  32
// Symmetric-compressed feature rows:
//   [0,32)    linear k_i                          (weight a1 = 1)
//   [32,512)  s-blocks s=1..15: k_i * k_{(i+s)&31} (weight 1 = 2*a2, pair once)
//   [512,528) s=16:     k_i * k_{i+16}, i<16       (weight 1)
//   [528,560) diagonal  0.5 * k_i^2                (weight a2 = 0.5)
//   560       const 1                              (a0 term)
//   [561,576) pad (zero)
#define NF   576
#define NE   33
#define NKT  18
#define GTF_BH (NKT * 3 * 64 * 8)   // 27648 halves per bh
#define GTF_HALF (9 * 3 * 64 * 8)   // 13824 halves per staging phase
#define KC   16
#define NSTG 2                       // (NTOK/KC)/128
#define NVB  (KC * NBH)              // 512 blocks
#define NP8  (NBH * NE * NF / 8)     // 76032

typedef _Float16 half_t;
typedef _Float16 half8 __attribute__((ext_vector_type(8)));
typedef _Float16 half4v __attribute__((ext_vector_type(4)));
typedef float f32x4 __attribute__((ext_vector_type(4)));
typedef unsigned int u32;

#define MFMA16(A,B,C) __builtin_amdgcn_mfma_f32_16x16x32_f16((A),(B),(C),0,0,0)

// async 16B global->LDS: lds dst = wave-uniform base + lane*16
#define ASYNC_CP16(dst_lds, src_glb) \
    __builtin_amdgcn_global_load_lds( \
        (const __attribute__((address_space(1))) u32*)(const void*)(src_glb), \
        (__attribute__((address_space(3))) u32*)(void*)(dst_lds), 16, 0, 0)

static __device__ __forceinline__ half8 splat8(half_t x) {
    return (half8){x, x, x, x, x, x, x, x};
}

// LDS group-swizzle for ta's transpose staging.
static __device__ __forceinline__ int FS(int d) { return (d + (d >> 3)) & 15; }

// ---------------------------------------------------------------------------
// TA: fused transpose + G-build (r12 arithmetic, COMPACT CODE):
// kk loop and stage loop are NOT unrolled (#pragma unroll 1) — only the mt
// loop stays unrolled (acc[] must be statically indexed). ~8x smaller code
// to relieve L1I streaming, which is the standing theory for the 45 us wall
// (all pipes <10% busy, occupancy-insensitive, worse with more waves).
// ---------------------------------------------------------------------------
__global__ __launch_bounds__(256, 2)
void ta_kernel(const float* __restrict__ kin, const float* __restrict__ vin,
               half_t* __restrict__ P)
{
    __shared__ __align__(16) half_t kb0[2 * 4096];
    __shared__ __align__(16) half_t vb0[2 * 4096];

    const int vb = blockIdx.x;
    const int bh = vb & (NBH - 1), kc = vb >> 5;
    const int t = threadIdx.x;
    const int w = t >> 6, lane = t & 63, l16 = lane & 15, quad = lane >> 4;
    const int pw = w * 144;
    const half8 h05 = splat8((half_t)0.5f);

    f32x4 acc[9][3];
    #pragma unroll
    for (int m = 0; m < 9; ++m)
        #pragma unroll
        for (int e = 0; e < 3; ++e)
            acc[m][e] = (f32x4){0.f, 0.f, 0.f, 0.f};

    // rotated-row metadata for s-block tiles (per-mt registers, static index)
    int rotoff[9], rotsalt[9];
    #pragma unroll
    for (int mt = 0; mt < 9; ++mt) {
        const int pm = pw + mt * 16;
        int ro = 0, rs = 0;
        if (pm >= 32 && pm < 512) {
            const int s  = 1 + ((pm - 32) >> 5);
            const int i0 = (pm - 32) & 31;
            const int r  = (i0 + l16 + s) & 31;
            ro = r * 128;
            rs = FS(r);
        }
        rotoff[mt] = ro;
        rotsalt[mt] = rs;
    }
    const int sh0 = FS(l16), sh1 = FS(l16 + 16);

    const size_t fbase = ((size_t)bh * NTOK + kc * 256) * 32;  // float index
    const float4* k4 = (const float4*)kin + fbase / 4;
    const float4* v4 = (const float4*)vin + fbase / 4;

    float kaf[16], vaf[16];
    auto loadst = [&](int s) {
        const int base = s * 1024;   // 128 tokens * 8 float4/token
        #pragma unroll
        for (int r = 0; r < 4; ++r) {
            float4 kk = k4[base + t + 256 * r];
            float4 vv = v4[base + t + 256 * r];
            kaf[4*r+0] = kk.x; kaf[4*r+1] = kk.y; kaf[4*r+2] = kk.z; kaf[4*r+3] = kk.w;
            vaf[4*r+0] = vv.x; vaf[4*r+1] = vv.y; vaf[4*r+2] = vv.z; vaf[4*r+3] = vv.w;
        }
    };
    auto writest = [&](int buf) {
        half_t* kb = kb0 + buf * 4096;
        half_t* vb2 = vb0 + buf * 4096;
        #pragma unroll
        for (int r = 0; r < 4; ++r) {
            const int fi = t + 256 * r;
            const int n = fi >> 3, d4 = fi & 7;
            const int c = n >> 3, j = n & 7;
            #pragma unroll
            for (int i = 0; i < 4; ++i) {
                const int d = 4 * d4 + i;
                const int a = d * 128 + ((c ^ FS(d)) << 3) + j;
                kb[a] = (half_t)kaf[4*r+i];
                vb2[a] = (half_t)vaf[4*r+i];
            }
        }
    };
    auto compute = [&](int buf) {
        const half_t* kb = kb0 + buf * 4096;
        const half_t* vbp = vb0 + buf * 4096;
        #pragma unroll 1
        for (int kk = 0; kk < 4; ++kk) {
            const int c = kk * 4 + quad;
            half8 kj0 = *(const half8*)&kb[l16 * 128 + ((c ^ sh0) << 3)];
            half8 kj1 = *(const half8*)&kb[(l16 + 16) * 128 + ((c ^ sh1) << 3)];
            half8 bf0 = *(const half8*)&vbp[l16 * 128 + ((c ^ sh0) << 3)];
            half8 bf1 = *(const half8*)&vbp[(l16 + 16) * 128 + ((c ^ sh1) << 3)];
            half_t onec = (l16 == 0) ? (half_t)1 : (half_t)0;
            half8 bf2 = splat8(onec);
            #pragma unroll
            for (int mt = 0; mt < 9; ++mt) {
                const int pm = pw + mt * 16;
                half8 af;
                if (pm < 32) {
                    af = pm ? kj1 : kj0;                       // linear
                } else if (pm < 512) {
                    half8 rot = *(const half8*)&kb[rotoff[mt] + ((c ^ rotsalt[mt]) << 3)];
                    af = (((pm - 32) & 16) ? kj1 : kj0) * rot; // pair {i, i+s}
                } else if (pm == 512) {
                    af = kj0 * kj1;                            // s=16 pairs
                } else if (pm == 528) {
                    af = (kj0 * h05) * kj0;                    // diag i<16
                } else if (pm == 544) {
                    af = (kj1 * h05) * kj1;                    // diag i>=16
                } else {
                    af = bf2;                                  // const row (560)
                }
                acc[mt][0] = MFMA16(af, bf0, acc[mt][0]);
                acc[mt][1] = MFMA16(af, bf1, acc[mt][1]);
                acc[mt][2] = MFMA16(af, bf2, acc[mt][2]);
            }
        }
    };

    loadst(0);
    writest(0);
    __syncthreads();
    #pragma unroll 1
    for (int st = 0; st < NSTG; ++st) {
        const int cur = st & 1;
        if (st + 1 < NSTG) loadst(st + 1);     // issue early: hides under MFMAs
        compute(cur);
        if (st + 1 < NSTG) { writest(cur ^ 1); __syncthreads(); }
    }

    half_t* Pb = P + ((size_t)kc * NBH + bh) * NE * NF;
    #pragma unroll
    for (int mt = 0; mt < 9; ++mt) {
        int p0 = pw + mt * 16 + quad * 4;
        half4v h0 = {(half_t)acc[mt][0][0], (half_t)acc[mt][0][1],
                     (half_t)acc[mt][0][2], (half_t)acc[mt][0][3]};
        half4v h1 = {(half_t)acc[mt][1][0], (half_t)acc[mt][1][1],
                     (half_t)acc[mt][1][2], (half_t)acc[mt][1][3]};
        *(half4v*)&Pb[(size_t)l16 * NF + p0] = h0;
        *(half4v*)&Pb[(size_t)(l16 + 16) * NF + p0] = h1;
        if (l16 == 0) {
            half4v h2 = {(half_t)acc[mt][2][0], (half_t)acc[mt][2][1],
                         (half_t)acc[mt][2][2], (half_t)acc[mt][2][3]};
            *(half4v*)&Pb[(size_t)32 * NF + p0] = h2;
        }
    }
}

// ---------------------------------------------------------------------------
// AR: reduce KC fp16 partial planes (fp32 accum) -> GtF fragment order:
//   GtF[bh][kt(18)][rr(3)][lane=quad*16+l16][j(8)]   (r12-exact)
// ---------------------------------------------------------------------------
__global__ __launch_bounds__(256)
void ar_kernel(const half_t* __restrict__ P, half_t* __restrict__ GtF)
{
    const int idx = blockIdx.x * 256 + threadIdx.x;
    if (idx >= NP8) return;
    float s[8] = {0.f, 0.f, 0.f, 0.f, 0.f, 0.f, 0.f, 0.f};
    for (int c = 0; c < KC; ++c) {
        half8 h = *(const half8*)&P[(size_t)c * (NBH * NE * NF) + (size_t)idx * 8];
        #pragma unroll
        for (int j = 0; j < 8; ++j) s[j] += (float)h[j];
    }
    half8 o;
    #pragma unroll
    for (int j = 0; j < 8; ++j) o[j] = (half_t)s[j];
    int row = idx / 72;                  // NF/8
    int p8 = idx - row * 72;
    int e = row % 33, bhh = row / 33;
    int kt = p8 >> 2, quad = p8 & 3;
    int rr = e >> 4, l16 = e & 15;       // e==32 -> rr=2, l16=0
    size_t dst8 = (size_t)bhh * (GTF_BH / 8)
                + (size_t)(kt * 3 + rr) * 64 + quad * 16 + l16;
    *(half8*)&GtF[dst8 * 8] = o;
}

// ---------------------------------------------------------------------------
// B: out[n][e] = (phi(q_n).G[:,e]) / (phi(q_n).G[:,32]) via f16 MFMA over
// 18 feature chunks. GtF bh-slice staged into LDS via global_load_lds in two
// phases; fragments via contiguous ds_read_b128. (r12-exact.)
// ---------------------------------------------------------------------------
__global__ __launch_bounds__(256)
void b_kernel(const float* __restrict__ qin, const half_t* __restrict__ GtF,
              float* __restrict__ out)
{
    const int bh = blockIdx.x, mbq = blockIdx.y;   // 32 x 16
    const int t = threadIdx.x, w = t >> 6, lane = t & 63;
    const int l16 = lane & 15, quad = lane >> 4;
    __shared__ __align__(16) half_t qs2[256 * 56];     // 28672 B
    __shared__ __align__(16) half_t gs[GTF_HALF];      // 27648 B (9 kt)
    __shared__ float denl[256];                        // 1024 B
    const size_t nbase = (size_t)bh * NTOK + mbq * 256;

    // cooperative GtF staging: 27 chunks of 1 KB (64 lanes x 16 B), linear copy
    const half_t* Gsrc = GtF + (size_t)bh * GTF_BH + (size_t)lane * 8;
    auto stage = [&](int phase) {
        const half_t* src = Gsrc + phase * GTF_HALF;
        #pragma unroll
        for (int i = 0; i < 7; ++i) {
            const int c = w + 4 * i;
            if (c < 27)
                ASYNC_CP16(gs + c * 512, src + c * 512);
        }
    };
    stage(0);   // kt 0..8 in flight; hides under the q staging below

    const float4* q4 = (const float4*)(qin + nbase * 32);
    #pragma unroll
    for (int r = 0; r < 8; ++r) {
        int f4 = t + 256 * r, n = f4 >> 3, d4 = f4 & 7;
        float4 vv = q4[f4];
        half4v h = {(half_t)vv.x, (half_t)vv.y, (half_t)vv.z, (half_t)vv.w};
        *(half4v*)&qs2[n * 56 + d4 * 4] = h;
        if (d4 < 4) *(half4v*)&qs2[n * 56 + 32 + d4 * 4] = h;  // wrap dims 0..15
    }
    __syncthreads();   // drains async copies (vmcnt) + qs2 writes

    const int rbase = w * 64;
    int tb[4];
    #pragma unroll
    for (int mt = 0; mt < 4; ++mt) tb[mt] = (rbase + mt * 16 + l16) * 56;

    half8 vq[4], hv[4], gv[4];
    #pragma unroll
    for (int mt = 0; mt < 4; ++mt) {
        const int qb = tb[mt] + quad * 8;
        vq[mt] = *(const half8*)&qs2[qb];
        hv[mt] = *(const half8*)&qs2[qb + 8];
        gv[mt] = *(const half8*)&qs2[qb + 16];
    }

    f32x4 acc[3][4];
    #pragma unroll
    for (int a = 0; a < 3; ++a)
        #pragma unroll
        for (int b = 0; b < 4; ++b)
            acc[a][b] = (f32x4){0.f, 0.f, 0.f, 0.f};

    // fragment read from LDS: contiguous 16B/lane (conflict-free b128 pattern)
#define LDB(ktL, B) do { \
    _Pragma("unroll") \
    for (int rr = 0; rr < 3; ++rr) \
        (B)[rr] = *(const half8*)&gs[(((ktL) * 3 + rr) * 64 + lane) * 8]; \
} while (0)

#define DO_MFMA(AF, B) do { \
    _Pragma("unroll") \
    for (int mt = 0; mt < 4; ++mt) { \
        acc[0][mt] = MFMA16((AF)[mt], (B)[0], acc[0][mt]); \
        acc[1][mt] = MFMA16((AF)[mt], (B)[1], acc[1][mt]); \
        acc[2][mt] = MFMA16((AF)[mt], (B)[2], acc[2][mt]); \
    } \
} while (0)

#define QCHUNK(S, KTL) do { \
    half8 Bc[3]; \
    LDB((KTL), Bc); \
    half8 af[4]; \
    _Pragma("unroll") \
    for (int mt = 0; mt < 4; ++mt) { \
        half8 lo = ((S) < 8) ? vq[mt] : hv[mt]; \
        half8 hi = ((S) < 8) ? hv[mt] : gv[mt]; \
        half8 rot = __builtin_shufflevector(lo, hi, \
            ((S) & 7) + 0, ((S) & 7) + 1, ((S) & 7) + 2, ((S) & 7) + 3, \
            ((S) & 7) + 4, ((S) & 7) + 5, ((S) & 7) + 6, ((S) & 7) + 7); \
        af[mt] = vq[mt] * rot; \
    } \
    DO_MFMA(af, Bc); \
} while (0)

    // ---- phase A: kt 0..8 (resident in gs) ----
    {   // kt = 0: linear features
        half8 Bc[3];
        LDB(0, Bc);
        DO_MFMA(vq, Bc);
    }
    QCHUNK(1, 1);  QCHUNK(2, 2);  QCHUNK(3, 3);  QCHUNK(4, 4);
    QCHUNK(5, 5);  QCHUNK(6, 6);  QCHUNK(7, 7);  QCHUNK(8, 8);

    // ---- restage: kt 9..17 ----
    __syncthreads();   // all waves done reading phase-A gs
    stage(1);
    __syncthreads();   // copies drained (vmcnt waited before barrier)

    // ---- phase B: kt 9..17 (local indices 0..8) ----
    QCHUNK(9, 0);  QCHUNK(10, 1); QCHUNK(11, 2); QCHUNK(12, 3);
    QCHUNK(13, 4); QCHUNK(14, 5); QCHUNK(15, 6);

    {   // kt = 16 (local 7): quads 0,1: s16 pairs; quads 2,3: diag blocks 0,1
        half8 Bc[3];
        LDB(7, Bc);
        half8 af[4];
        #pragma unroll
        for (int mt = 0; mt < 4; ++mt) {
            const int off = tb[mt] + ((quad >= 2) ? (quad - 2) : quad) * 8;
            half8 Ld = *(const half8*)&qs2[off];
            af[mt] = (quad < 2) ? (vq[mt] * gv[mt]) : (Ld * Ld);
        }
        DO_MFMA(af, Bc);
    }
    {   // kt = 17 (local 8): quads 0,1: diag blocks 2,3; quad 2: const e0; quad 3: pad
        half8 Bc[3];
        LDB(8, Bc);
        const half8 zero = {};
        half8 c10 = {};
        c10[0] = (half_t)1;
        half8 af[4];
        #pragma unroll
        for (int mt = 0; mt < 4; ++mt) {
            half8 d = gv[mt] * gv[mt];
            af[mt] = (quad < 2) ? d : ((quad == 2) ? c10 : zero);
        }
        DO_MFMA(af, Bc);
    }
#undef QCHUNK
#undef DO_MFMA
#undef LDB

    if (l16 == 0) {
        #pragma unroll
        for (int mt = 0; mt < 4; ++mt)
            #pragma unroll
            for (int r = 0; r < 4; ++r)
                denl[rbase + mt * 16 + quad * 4 + r] = acc[2][mt][r];
    }
    __syncthreads();
    #pragma unroll
    for (int mt = 0; mt < 4; ++mt) {
        float inv[4];
        #pragma unroll
        for (int r = 0; r < 4; ++r)
            inv[r] = __builtin_amdgcn_rcpf(denl[rbase + mt * 16 + quad * 4 + r]);
        #pragma unroll
        for (int r = 0; r < 4; ++r) {
            size_t ro = (nbase + rbase + mt * 16 + quad * 4 + r) * 32;
            out[ro + l16] = acc[0][mt][r] * inv[r];
            out[ro + l16 + 16] = acc[1][mt][r] * inv[r];
        }
    }
}

// ---------------------------------------------------------------------------
extern "C" void kernel_launch(void* const* d_in, const int* in_sizes, int n_in,
                              void* d_out, int out_size, void* d_ws, size_t ws_size,
                              hipStream_t stream)
{
    const float* q = (const float*)d_in[0];
    const float* k = (const float*)d_in[1];
    const float* v = (const float*)d_in[2];
    float* out = (float*)d_out;

    const size_t planeHalves = (size_t)NBH * NE * NF;      // 608256
    half_t* P = (half_t*)d_ws;                             // 16 planes: 19.5 MB
    half_t* GtF = P + (size_t)KC * planeHalves;            // 1.77 MB

    ta_kernel<<<dim3(NVB), 256, 0, stream>>>(k, v, P);
    ar_kernel<<<dim3((NP8 + 255) / 256), 256, 0, stream>>>(P, GtF);
    b_kernel<<<dim3(NBH, 16), 256, 0, stream>>>(q, GtF, out);
}